// Round 3
// baseline (136.635 us; speedup 1.0000x reference)
//
#include <hip/hip_runtime.h>

#define N_ATOMS 262144
#define NGRAPH  2048
#define INV_SCALE 0.17677669529663687f  // 1/sqrt(32)

// ---------------- K1: P[h][i] = sum_d Wk[i][h*32+d]*q[h][d];  c[h] = bk_h . q_h
__global__ void k_prep(const float* __restrict__ Wk, const float* __restrict__ bk,
                       const float* __restrict__ q, float* __restrict__ P,
                       float* __restrict__ c) {
  int h = blockIdx.x, i = threadIdx.x;
  float s = 0.f;
  #pragma unroll
  for (int d = 0; d < 32; ++d)
    s = fmaf(Wk[i * 256 + h * 32 + d], q[h * 32 + d], s);
  P[h * 256 + i] = s;
  if (i == 0) {
    float cc = 0.f;
    #pragma unroll
    for (int d = 0; d < 32; ++d) cc = fmaf(bk[h * 32 + d], q[h * 32 + d], cc);
    c[h] = cc;
  }
}

// ---------------- K1b: segment bounds via one binary search per graph.
__global__ void k_bounds(const int* __restrict__ batch, int* __restrict__ bounds) {
  int g = blockIdx.x * blockDim.x + threadIdx.x;
  if (g >= NGRAPH) return;
  int lo = 0, hi = N_ATOMS;
  while (lo < hi) {
    int mid = (lo + hi) >> 1;
    if (batch[mid] < g) lo = mid + 1; else hi = mid;
  }
  bounds[2 * g] = lo;
  if (g > 0) bounds[2 * g - 1] = lo;
  if (g == NGRAPH - 1) bounds[2 * g + 1] = N_ATOMS;
}

__device__ inline void fma4(float4& a, float s, const float4& v) {
  a.x = fmaf(s, v.x, a.x); a.y = fmaf(s, v.y, a.y);
  a.z = fmaf(s, v.z, a.z); a.w = fmaf(s, v.w, a.w);
}

// ---------------- K2: fused single-pass scores + exp + weighted accumulate.
// One block per graph, 4 waves; wave handles atoms n%4.
// Lane mapping: g = lane>>3 (feature block of 32), h = lane&7 (head).
// Lane owns (head h) x (features g*32..g*32+31): dot partial needs only a
// 3-shfl butterfly over g-bits (xor 8,16,32); no e-broadcast needed since the
// lane accumulates A for its own head over its own features.
__global__ __launch_bounds__(256) void k_fused(const float* __restrict__ x,
                                               const float* __restrict__ P,
                                               const float* __restrict__ c,
                                               const int* __restrict__ bounds,
                                               float* __restrict__ Ag) {
  int b = blockIdx.x;
  int s = bounds[2 * b], e = bounds[2 * b + 1];
  int t = threadIdx.x, lane = t & 63, wv = t >> 6;
  int g = lane >> 3, h = lane & 7;

  float4 Pv[8];
  #pragma unroll
  for (int i = 0; i < 8; ++i)
    Pv[i] = *reinterpret_cast<const float4*>(P + h * 256 + g * 32 + i * 4);
  float cl = c[h];

  float4 A[8];
  #pragma unroll
  for (int i = 0; i < 8; ++i) A[i] = make_float4(0.f, 0.f, 0.f, 0.f);
  float dacc = 0.f;

  for (int n = s + wv; n < e; n += 4) {
    const float* xr = x + (size_t)n * 256 + g * 32;
    float4 xv[8];
    #pragma unroll
    for (int i = 0; i < 8; ++i)
      xv[i] = *reinterpret_cast<const float4*>(xr + i * 4);
    float a0 = 0.f, a1 = 0.f, a2 = 0.f, a3 = 0.f;
    #pragma unroll
    for (int i = 0; i < 8; ++i) {
      a0 = fmaf(xv[i].x, Pv[i].x, a0);
      a1 = fmaf(xv[i].y, Pv[i].y, a1);
      a2 = fmaf(xv[i].z, Pv[i].z, a2);
      a3 = fmaf(xv[i].w, Pv[i].w, a3);
    }
    float r = (a0 + a1) + (a2 + a3);
    r += __shfl_xor(r, 8, 64);
    r += __shfl_xor(r, 16, 64);
    r += __shfl_xor(r, 32, 64);
    float ev = __expf((r + cl) * INV_SCALE);
    dacc += ev;
    #pragma unroll
    for (int i = 0; i < 8; ++i) fma4(A[i], ev, xv[i]);
  }

  // epilogue: cross-wave reduce + normalize.
  // As row stride = 36 floats (144B, 16B-aligned) -> b128 writes at most
  // 8-way bank aliased, reads 2-way (free); once per block.
  __shared__ float As[4][64][36];  // ~36.9 KB
  __shared__ float dws[4][64];
  __shared__ float dinv[8];
  #pragma unroll
  for (int i = 0; i < 8; ++i)
    *reinterpret_cast<float4*>(&As[wv][lane][4 * i]) = A[i];
  dws[wv][lane] = dacc;
  __syncthreads();
  if (t < 8) {
    float ds = dws[0][t] + dws[1][t] + dws[2][t] + dws[3][t];
    dinv[t] = ds > 0.f ? 1.0f / ds : 0.f;
  }
  __syncthreads();
  // output o = h*256 + f, h = r2, f = t; source lane ln = (f>>5)*8 + h, j = f&31
  #pragma unroll
  for (int r2 = 0; r2 < 8; ++r2) {
    int ln = ((t >> 5) << 3) + r2;
    int j = t & 31;
    float v = As[0][ln][j] + As[1][ln][j] + As[2][ln][j] + As[3][ln][j];
    Ag[(size_t)b * 2048 + r2 * 256 + t] = v * dinv[r2];
  }
}

// ---------------- K5: att = A . Wv + bv (nonempty), out = att . Wo + bo
// block handles 4 graphs; thread t = output column.
__global__ __launch_bounds__(256) void k_out(const float* __restrict__ Ag,
                                             const int* __restrict__ bounds,
                                             const float* __restrict__ Wv,
                                             const float* __restrict__ bv,
                                             const float* __restrict__ Wo,
                                             const float* __restrict__ bo,
                                             float* __restrict__ out) {
  __shared__ float Alds[4 * 2048];   // 32 KB
  __shared__ float attlds[4 * 256];  // 4 KB
  __shared__ float eflag[4];
  int b0 = blockIdx.x * 4;
  int t = threadIdx.x;
  #pragma unroll
  for (int r = 0; r < 32; ++r) {
    int idx = r * 256 + t;
    Alds[idx] = Ag[(size_t)b0 * 2048 + idx];
  }
  if (t < 4) {
    int s = bounds[2 * (b0 + t)], e = bounds[2 * (b0 + t) + 1];
    eflag[t] = (e > s) ? 1.0f : 0.0f;
  }
  __syncthreads();
  int h = t >> 5;
  float bvk = bv[t];
  float acc[4];
  #pragma unroll
  for (int g = 0; g < 4; ++g) acc[g] = 0.f;
  for (int i4 = 0; i4 < 64; ++i4) {
    float aa[4][4];
    #pragma unroll
    for (int g = 0; g < 4; ++g) {
      float4 v = *reinterpret_cast<const float4*>(&Alds[g * 2048 + h * 256 + i4 * 4]);
      aa[g][0] = v.x; aa[g][1] = v.y; aa[g][2] = v.z; aa[g][3] = v.w;
    }
    #pragma unroll
    for (int j = 0; j < 4; ++j) {
      float wvv = Wv[(size_t)(i4 * 4 + j) * 256 + t];
      #pragma unroll
      for (int g = 0; g < 4; ++g) acc[g] = fmaf(aa[g][j], wvv, acc[g]);
    }
  }
  #pragma unroll
  for (int g = 0; g < 4; ++g) attlds[g * 256 + t] = acc[g] + bvk * eflag[g];
  __syncthreads();
  float boj = bo[t];
  float o[4];
  #pragma unroll
  for (int g = 0; g < 4; ++g) o[g] = boj;
  for (int k4 = 0; k4 < 64; ++k4) {
    float aa[4][4];
    #pragma unroll
    for (int g = 0; g < 4; ++g) {
      float4 v = *reinterpret_cast<const float4*>(&attlds[g * 256 + k4 * 4]);
      aa[g][0] = v.x; aa[g][1] = v.y; aa[g][2] = v.z; aa[g][3] = v.w;
    }
    #pragma unroll
    for (int j = 0; j < 4; ++j) {
      float wo = Wo[(size_t)(k4 * 4 + j) * 256 + t];
      #pragma unroll
      for (int g = 0; g < 4; ++g) o[g] = fmaf(aa[g][j], wo, o[g]);
    }
  }
  #pragma unroll
  for (int g = 0; g < 4; ++g) out[(size_t)(b0 + g) * 256 + t] = o[g];
}

extern "C" void kernel_launch(void* const* d_in, const int* in_sizes, int n_in,
                              void* d_out, int out_size, void* d_ws, size_t ws_size,
                              hipStream_t stream) {
  const float* x   = (const float*)d_in[0];
  const int*   bat = (const int*)d_in[1];
  const float* q   = (const float*)d_in[2];
  const float* Wk  = (const float*)d_in[3];
  const float* bk  = (const float*)d_in[4];
  const float* Wv  = (const float*)d_in[5];
  const float* bv  = (const float*)d_in[6];
  const float* Wo  = (const float*)d_in[7];
  const float* bo  = (const float*)d_in[8];
  float* out = (float*)d_out;

  float* ws = (float*)d_ws;
  float* P      = ws;                 // 2048 floats
  float* c      = ws + 2048;          // 8 floats
  int*   bounds = (int*)(ws + 4096);  // 4096 ints
  float* Ag     = ws + 8192;          // 2048*2048 floats

  k_prep<<<8, 256, 0, stream>>>(Wk, bk, q, P, c);
  k_bounds<<<8, 256, 0, stream>>>(bat, bounds);
  k_fused<<<NGRAPH, 256, 0, stream>>>(x, P, c, bounds, Ag);
  k_out<<<NGRAPH / 4, 256, 0, stream>>>(Ag, bounds, Wv, bv, Wo, bo, out);
}

// Round 4
// 116.839 us; speedup vs baseline: 1.1694x; 1.1694x over previous
//
#include <hip/hip_runtime.h>

#define N_ATOMS 262144
#define NGRAPH  2048
#define INV_SCALE 0.17677669529663687f  // 1/sqrt(32)

// ---------------- K1: P[h][i] = sum_d Wk[i][h*32+d]*q[h][d];  c[h] = bk_h . q_h
__global__ void k_prep(const float* __restrict__ Wk, const float* __restrict__ bk,
                       const float* __restrict__ q, float* __restrict__ P,
                       float* __restrict__ c) {
  int h = blockIdx.x, i = threadIdx.x;
  float s = 0.f;
  #pragma unroll
  for (int d = 0; d < 32; ++d)
    s = fmaf(Wk[i * 256 + h * 32 + d], q[h * 32 + d], s);
  P[h * 256 + i] = s;
  if (i == 0) {
    float cc = 0.f;
    #pragma unroll
    for (int d = 0; d < 32; ++d) cc = fmaf(bk[h * 32 + d], q[h * 32 + d], cc);
    c[h] = cc;
  }
}

// ---------------- K1b: segment bounds via one binary search per graph.
__global__ void k_bounds(const int* __restrict__ batch, int* __restrict__ bounds) {
  int g = blockIdx.x * blockDim.x + threadIdx.x;
  if (g >= NGRAPH) return;
  int lo = 0, hi = N_ATOMS;
  while (lo < hi) {
    int mid = (lo + hi) >> 1;
    if (batch[mid] < g) lo = mid + 1; else hi = mid;
  }
  bounds[2 * g] = lo;
  if (g > 0) bounds[2 * g - 1] = lo;
  if (g == NGRAPH - 1) bounds[2 * g + 1] = N_ATOMS;
}

__device__ inline void fma4(float4& a, float s, const float4& v) {
  a.x = fmaf(s, v.x, a.x); a.y = fmaf(s, v.y, a.y);
  a.z = fmaf(s, v.z, a.z); a.w = fmaf(s, v.w, a.w);
}

// transpose-reduce: 8 head-partials/lane over 64 lanes -> full dot of head h at
// every lane (head ownership pattern h(lane) = bit-mix). Verified in R2.
__device__ __forceinline__ float fold8(float acc[8], int lane) {
  {
    int m = lane & 8;
    float nw[4];
    #pragma unroll
    for (int j = 0; j < 4; ++j) {
      float snd = m ? acc[j] : acc[j + 4];
      float rcv = __shfl_xor(snd, 8, 64);
      nw[j] = (m ? acc[j + 4] : acc[j]) + rcv;
    }
    #pragma unroll
    for (int j = 0; j < 4; ++j) acc[j] = nw[j];
  }
  {
    int m = lane & 16;
    float nw[2];
    #pragma unroll
    for (int j = 0; j < 2; ++j) {
      float snd = m ? acc[j] : acc[j + 2];
      float rcv = __shfl_xor(snd, 16, 64);
      nw[j] = (m ? acc[j + 2] : acc[j]) + rcv;
    }
    acc[0] = nw[0]; acc[1] = nw[1];
  }
  float r;
  {
    int m = lane & 32;
    float snd = m ? acc[0] : acc[1];
    float rcv = __shfl_xor(snd, 32, 64);
    r = (m ? acc[1] : acc[0]) + rcv;
  }
  r += __shfl_xor(r, 1, 64);
  r += __shfl_xor(r, 2, 64);
  r += __shfl_xor(r, 4, 64);
  return r;
}

// broadcast: lane holds e of its own head h -> e8[k] = e of head k, all lanes.
// Verified in R2.
__device__ __forceinline__ void bcast8(float ev, int h, float e8[8]) {
  float o = __shfl_xor(ev, 32, 64);
  float p0 = (h & 1) ? o : ev;
  float p1 = (h & 1) ? ev : o;
  float q0 = __shfl_xor(p0, 16, 64);
  float q1 = __shfl_xor(p1, 16, 64);
  float f0, f1, f2, f3;
  if (h & 2) { f0 = q0; f1 = q1; f2 = p0; f3 = p1; }
  else       { f0 = p0; f1 = p1; f2 = q0; f3 = q1; }
  float g0 = __shfl_xor(f0, 8, 64);
  float g1 = __shfl_xor(f1, 8, 64);
  float g2 = __shfl_xor(f2, 8, 64);
  float g3 = __shfl_xor(f3, 8, 64);
  if (h & 4) { e8[0]=g0; e8[1]=g1; e8[2]=g2; e8[3]=g3; e8[4]=f0; e8[5]=f1; e8[6]=f2; e8[7]=f3; }
  else       { e8[0]=f0; e8[1]=f1; e8[2]=f2; e8[3]=f3; e8[4]=g0; e8[5]=g1; e8[6]=g2; e8[7]=g3; }
}

// ---------------- K2: fused single-pass scores + exp + weighted accumulate.
// One block per graph, 4 waves. Lane l = features 4l..4l+3 (coalesced 1KB/wave
// loads). TWO atoms per iteration per wave: two independent 17-shfl chains
// interleave, doubling bytes-in-flight per wave to hide shuffle latency.
__global__ __launch_bounds__(256) void k_fused(const float* __restrict__ x,
                                               const float* __restrict__ P,
                                               const float* __restrict__ c,
                                               const int* __restrict__ bounds,
                                               float* __restrict__ Ag) {
  int b = blockIdx.x;
  int s = bounds[2 * b], e = bounds[2 * b + 1];
  int t = threadIdx.x, lane = t & 63, wv = t >> 6;
  int h = ((lane >> 1) & 4) | ((lane >> 3) & 2) | ((lane >> 5) & 1);

  float4 Pl[8];
  #pragma unroll
  for (int k = 0; k < 8; ++k)
    Pl[k] = *reinterpret_cast<const float4*>(P + k * 256 + 4 * lane);
  float cl = c[h];

  float4 A[8];
  #pragma unroll
  for (int k = 0; k < 8; ++k) A[k] = make_float4(0.f, 0.f, 0.f, 0.f);
  float dacc = 0.f;

  for (int n0 = s + 2 * wv; n0 < e; n0 += 8) {
    bool has2 = (n0 + 1) < e;
    int n1 = has2 ? n0 + 1 : n0;
    float4 xv0 = *reinterpret_cast<const float4*>(x + (size_t)n0 * 256 + 4 * lane);
    float4 xv1 = *reinterpret_cast<const float4*>(x + (size_t)n1 * 256 + 4 * lane);
    float acc0[8], acc1[8];
    #pragma unroll
    for (int k = 0; k < 8; ++k) {
      acc0[k] = fmaf(xv0.x, Pl[k].x,
                fmaf(xv0.y, Pl[k].y, fmaf(xv0.z, Pl[k].z, xv0.w * Pl[k].w)));
      acc1[k] = fmaf(xv1.x, Pl[k].x,
                fmaf(xv1.y, Pl[k].y, fmaf(xv1.z, Pl[k].z, xv1.w * Pl[k].w)));
    }
    float r0 = fold8(acc0, lane);
    float r1 = fold8(acc1, lane);
    float ev0 = __expf((r0 + cl) * INV_SCALE);
    float ev1 = __expf((r1 + cl) * INV_SCALE);
    ev1 = has2 ? ev1 : 0.f;
    dacc += ev0 + ev1;
    float e80[8], e81[8];
    bcast8(ev0, h, e80);
    bcast8(ev1, h, e81);
    #pragma unroll
    for (int k = 0; k < 8; ++k) fma4(A[k], e80[k], xv0);
    #pragma unroll
    for (int k = 0; k < 8; ++k) fma4(A[k], e81[k], xv1);
  }

  // epilogue: cross-wave reduce + normalize (R2-verified layout).
  __shared__ float As[4][8][256];  // 32 KB
  __shared__ float dws[4][8];
  __shared__ float dinvs[8];
  #pragma unroll
  for (int k = 0; k < 8; ++k)
    *reinterpret_cast<float4*>(&As[wv][k][4 * lane]) = A[k];
  if ((lane & 7) == 0) dws[wv][h] = dacc;
  __syncthreads();
  if (t < 8) {
    float ds = dws[0][t] + dws[1][t] + dws[2][t] + dws[3][t];
    dinvs[t] = ds > 0.f ? 1.0f / ds : 0.f;
  }
  __syncthreads();
  #pragma unroll
  for (int r2 = 0; r2 < 8; ++r2) {
    float v = As[0][r2][t] + As[1][r2][t] + As[2][r2][t] + As[3][r2][t];
    Ag[(size_t)b * 2048 + r2 * 256 + t] = v * dinvs[r2];
  }
}

// ---------------- K5: att = A . Wv + bv (nonempty), out = att . Wo + bo
// block handles 4 graphs; thread t = output column.
__global__ __launch_bounds__(256) void k_out(const float* __restrict__ Ag,
                                             const int* __restrict__ bounds,
                                             const float* __restrict__ Wv,
                                             const float* __restrict__ bv,
                                             const float* __restrict__ Wo,
                                             const float* __restrict__ bo,
                                             float* __restrict__ out) {
  __shared__ float Alds[4 * 2048];   // 32 KB
  __shared__ float attlds[4 * 256];  // 4 KB
  __shared__ float eflag[4];
  int b0 = blockIdx.x * 4;
  int t = threadIdx.x;
  #pragma unroll
  for (int r = 0; r < 32; ++r) {
    int idx = r * 256 + t;
    Alds[idx] = Ag[(size_t)b0 * 2048 + idx];
  }
  if (t < 4) {
    int s = bounds[2 * (b0 + t)], e = bounds[2 * (b0 + t) + 1];
    eflag[t] = (e > s) ? 1.0f : 0.0f;
  }
  __syncthreads();
  int h = t >> 5;
  float bvk = bv[t];
  float acc[4];
  #pragma unroll
  for (int g = 0; g < 4; ++g) acc[g] = 0.f;
  for (int i4 = 0; i4 < 64; ++i4) {
    float aa[4][4];
    #pragma unroll
    for (int g = 0; g < 4; ++g) {
      float4 v = *reinterpret_cast<const float4*>(&Alds[g * 2048 + h * 256 + i4 * 4]);
      aa[g][0] = v.x; aa[g][1] = v.y; aa[g][2] = v.z; aa[g][3] = v.w;
    }
    #pragma unroll
    for (int j = 0; j < 4; ++j) {
      float wvv = Wv[(size_t)(i4 * 4 + j) * 256 + t];
      #pragma unroll
      for (int g = 0; g < 4; ++g) acc[g] = fmaf(aa[g][j], wvv, acc[g]);
    }
  }
  #pragma unroll
  for (int g = 0; g < 4; ++g) attlds[g * 256 + t] = acc[g] + bvk * eflag[g];
  __syncthreads();
  float boj = bo[t];
  float o[4];
  #pragma unroll
  for (int g = 0; g < 4; ++g) o[g] = boj;
  for (int k4 = 0; k4 < 64; ++k4) {
    float aa[4][4];
    #pragma unroll
    for (int g = 0; g < 4; ++g) {
      float4 v = *reinterpret_cast<const float4*>(&attlds[g * 256 + k4 * 4]);
      aa[g][0] = v.x; aa[g][1] = v.y; aa[g][2] = v.z; aa[g][3] = v.w;
    }
    #pragma unroll
    for (int j = 0; j < 4; ++j) {
      float wo = Wo[(size_t)(k4 * 4 + j) * 256 + t];
      #pragma unroll
      for (int g = 0; g < 4; ++g) o[g] = fmaf(aa[g][j], wo, o[g]);
    }
  }
  #pragma unroll
  for (int g = 0; g < 4; ++g) out[(size_t)(b0 + g) * 256 + t] = o[g];
}

extern "C" void kernel_launch(void* const* d_in, const int* in_sizes, int n_in,
                              void* d_out, int out_size, void* d_ws, size_t ws_size,
                              hipStream_t stream) {
  const float* x   = (const float*)d_in[0];
  const int*   bat = (const int*)d_in[1];
  const float* q   = (const float*)d_in[2];
  const float* Wk  = (const float*)d_in[3];
  const float* bk  = (const float*)d_in[4];
  const float* Wv  = (const float*)d_in[5];
  const float* bv  = (const float*)d_in[6];
  const float* Wo  = (const float*)d_in[7];
  const float* bo  = (const float*)d_in[8];
  float* out = (float*)d_out;

  float* ws = (float*)d_ws;
  float* P      = ws;                 // 2048 floats
  float* c      = ws + 2048;          // 8 floats
  int*   bounds = (int*)(ws + 4096);  // 4096 ints
  float* Ag     = ws + 8192;          // 2048*2048 floats

  k_prep<<<8, 256, 0, stream>>>(Wk, bk, q, P, c);
  k_bounds<<<8, 256, 0, stream>>>(bat, bounds);
  k_fused<<<NGRAPH, 256, 0, stream>>>(x, P, c, bounds, Ag);
  k_out<<<NGRAPH / 4, 256, 0, stream>>>(Ag, bounds, Wv, bv, Wo, bo, out);
}

// Round 5
// 103.023 us; speedup vs baseline: 1.3263x; 1.1341x over previous
//
#include <hip/hip_runtime.h>

#define N_ATOMS 262144
#define NGRAPH  2048
#define INV_SCALE 0.17677669529663687f  // 1/sqrt(32)

typedef float f32x2 __attribute__((ext_vector_type(2)));
typedef float f32x4 __attribute__((ext_vector_type(4)));

// CDNA packed fp32 (VOP3P). d = a*b+c per 32-bit half.
__device__ __forceinline__ f32x2 pk_mul(f32x2 a, f32x2 b) {
  f32x2 d; asm("v_pk_mul_f32 %0, %1, %2" : "=v"(d) : "v"(a), "v"(b)); return d;
}
__device__ __forceinline__ f32x2 pk_fma(f32x2 a, f32x2 b, f32x2 c) {
  f32x2 d; asm("v_pk_fma_f32 %0, %1, %2, %3" : "=v"(d) : "v"(a), "v"(b), "v"(c)); return d;
}
// broadcast LOW half of a to both halves (op_sel_hi[0]=0, op_sel[0]=0)
__device__ __forceinline__ f32x2 pk_fma_blo(f32x2 a, f32x2 b, f32x2 c) {
  f32x2 d; asm("v_pk_fma_f32 %0, %1, %2, %3 op_sel_hi:[0,1,1]"
               : "=v"(d) : "v"(a), "v"(b), "v"(c)); return d;
}
// broadcast HIGH half of a to both halves (op_sel[0]=1, default op_sel_hi[0]=1)
__device__ __forceinline__ f32x2 pk_fma_bhi(f32x2 a, f32x2 b, f32x2 c) {
  f32x2 d; asm("v_pk_fma_f32 %0, %1, %2, %3 op_sel:[1,0,0]"
               : "=v"(d) : "v"(a), "v"(b), "v"(c)); return d;
}

// ---------------- K1: P[h][i] = sum_d Wk[i][h*32+d]*q[h][d];  c[h] = bk_h . q_h
__global__ void k_prep(const float* __restrict__ Wk, const float* __restrict__ bk,
                       const float* __restrict__ q, float* __restrict__ P,
                       float* __restrict__ c) {
  int h = blockIdx.x, i = threadIdx.x;
  float s = 0.f;
  #pragma unroll
  for (int d = 0; d < 32; ++d)
    s = fmaf(Wk[i * 256 + h * 32 + d], q[h * 32 + d], s);
  P[h * 256 + i] = s;
  if (i == 0) {
    float cc = 0.f;
    #pragma unroll
    for (int d = 0; d < 32; ++d) cc = fmaf(bk[h * 32 + d], q[h * 32 + d], cc);
    c[h] = cc;
  }
}

// ---------------- K1b: segment bounds via one binary search per graph.
__global__ void k_bounds(const int* __restrict__ batch, int* __restrict__ bounds) {
  int g = blockIdx.x * blockDim.x + threadIdx.x;
  if (g >= NGRAPH) return;
  int lo = 0, hi = N_ATOMS;
  while (lo < hi) {
    int mid = (lo + hi) >> 1;
    if (batch[mid] < g) lo = mid + 1; else hi = mid;
  }
  bounds[2 * g] = lo;
  if (g > 0) bounds[2 * g - 1] = lo;
  if (g == NGRAPH - 1) bounds[2 * g + 1] = N_ATOMS;
}

// transpose-reduce: 8 head-partials/lane over 64 lanes -> full dot of head h at
// every lane (head ownership h(lane) = bit-mix of lane bits 3,4,5). R2-verified.
__device__ __forceinline__ float fold8(float acc[8], int lane) {
  {
    int m = lane & 8;
    float nw[4];
    #pragma unroll
    for (int j = 0; j < 4; ++j) {
      float snd = m ? acc[j] : acc[j + 4];
      float rcv = __shfl_xor(snd, 8, 64);
      nw[j] = (m ? acc[j + 4] : acc[j]) + rcv;
    }
    #pragma unroll
    for (int j = 0; j < 4; ++j) acc[j] = nw[j];
  }
  {
    int m = lane & 16;
    float nw[2];
    #pragma unroll
    for (int j = 0; j < 2; ++j) {
      float snd = m ? acc[j] : acc[j + 2];
      float rcv = __shfl_xor(snd, 16, 64);
      nw[j] = (m ? acc[j + 2] : acc[j]) + rcv;
    }
    acc[0] = nw[0]; acc[1] = nw[1];
  }
  float r;
  {
    int m = lane & 32;
    float snd = m ? acc[0] : acc[1];
    float rcv = __shfl_xor(snd, 32, 64);
    r = (m ? acc[1] : acc[0]) + rcv;
  }
  r += __shfl_xor(r, 1, 64);
  r += __shfl_xor(r, 2, 64);
  r += __shfl_xor(r, 4, 64);
  return r;
}

// ---------------- K2: fused single-pass scores + exp + weighted accumulate.
// One block per graph, 4 waves, 2 atoms/iter/wave. Lane l = features 4l..4l+3
// (coalesced 1KB/wave loads). e-values distributed via wave-private LDS table
// (replaces 7-shfl + ~24-cndmask bcast8). Packed f32 (v_pk_fma_f32) halves the
// fma count in dot and accumulate.
__global__ __launch_bounds__(256) void k_fused(const float* __restrict__ x,
                                               const float* __restrict__ P,
                                               const float* __restrict__ c,
                                               const int* __restrict__ bounds,
                                               float* __restrict__ Ag) {
  int b = blockIdx.x;
  int s = bounds[2 * b], e = bounds[2 * b + 1];
  int t = threadIdx.x, lane = t & 63, wv = t >> 6;
  int h = ((lane >> 1) & 4) | ((lane >> 3) & 2) | ((lane >> 5) & 1);

  // P fragments as packed pairs: Pl2[k][0] = P[k][4l..4l+1], [1] = 4l+2..4l+3
  f32x2 Pl2[8][2];
  #pragma unroll
  for (int k = 0; k < 8; ++k) {
    f32x4 pv = *reinterpret_cast<const f32x4*>(P + k * 256 + 4 * lane);
    Pl2[k][0] = __builtin_shufflevector(pv, pv, 0, 1);
    Pl2[k][1] = __builtin_shufflevector(pv, pv, 2, 3);
  }
  float cl = c[h];

  f32x2 A2[8][2];
  #pragma unroll
  for (int k = 0; k < 8; ++k) { A2[k][0] = (f32x2)0.f; A2[k][1] = (f32x2)0.f; }
  float dacc = 0.f;

  __shared__ float elds[4][2][8];  // [wave][atom-slot][head], wave-private

  for (int n0 = s + 2 * wv; n0 < e; n0 += 8) {
    bool has2 = (n0 + 1) < e;
    int n1 = has2 ? n0 + 1 : n0;
    f32x4 xq0 = *reinterpret_cast<const f32x4*>(x + (size_t)n0 * 256 + 4 * lane);
    f32x4 xq1 = *reinterpret_cast<const f32x4*>(x + (size_t)n1 * 256 + 4 * lane);
    f32x2 x0lo = __builtin_shufflevector(xq0, xq0, 0, 1);
    f32x2 x0hi = __builtin_shufflevector(xq0, xq0, 2, 3);
    f32x2 x1lo = __builtin_shufflevector(xq1, xq1, 0, 1);
    f32x2 x1hi = __builtin_shufflevector(xq1, xq1, 2, 3);

    float acc0[8], acc1[8];
    #pragma unroll
    for (int k = 0; k < 8; ++k) {
      f32x2 p0 = pk_fma(x0hi, Pl2[k][1], pk_mul(x0lo, Pl2[k][0]));
      f32x2 p1 = pk_fma(x1hi, Pl2[k][1], pk_mul(x1lo, Pl2[k][0]));
      acc0[k] = p0[0] + p0[1];
      acc1[k] = p1[0] + p1[1];
    }
    float r0 = fold8(acc0, lane);
    float r1 = fold8(acc1, lane);
    float ev0 = __expf((r0 + cl) * INV_SCALE);
    float ev1 = __expf((r1 + cl) * INV_SCALE);
    ev1 = has2 ? ev1 : 0.f;
    dacc += ev0 + ev1;

    // one writer per octet (h = bit-reversed octet index, bijective)
    if ((lane & 7) == 0) {
      elds[wv][0][h] = ev0;
      elds[wv][1][h] = ev1;
    }
    // same-wave LDS RAW: compiler inserts lgkmcnt; no barrier needed.
    f32x4 ea03 = *reinterpret_cast<const f32x4*>(&elds[wv][0][0]);
    f32x4 ea47 = *reinterpret_cast<const f32x4*>(&elds[wv][0][4]);
    f32x4 eb03 = *reinterpret_cast<const f32x4*>(&elds[wv][1][0]);
    f32x4 eb47 = *reinterpret_cast<const f32x4*>(&elds[wv][1][4]);
    f32x2 ea[4] = { __builtin_shufflevector(ea03, ea03, 0, 1),
                    __builtin_shufflevector(ea03, ea03, 2, 3),
                    __builtin_shufflevector(ea47, ea47, 0, 1),
                    __builtin_shufflevector(ea47, ea47, 2, 3) };
    f32x2 eb[4] = { __builtin_shufflevector(eb03, eb03, 0, 1),
                    __builtin_shufflevector(eb03, eb03, 2, 3),
                    __builtin_shufflevector(eb47, eb47, 0, 1),
                    __builtin_shufflevector(eb47, eb47, 2, 3) };
    #pragma unroll
    for (int j = 0; j < 4; ++j) {
      A2[2*j][0]   = pk_fma_blo(ea[j], x0lo, A2[2*j][0]);
      A2[2*j][1]   = pk_fma_blo(ea[j], x0hi, A2[2*j][1]);
      A2[2*j+1][0] = pk_fma_bhi(ea[j], x0lo, A2[2*j+1][0]);
      A2[2*j+1][1] = pk_fma_bhi(ea[j], x0hi, A2[2*j+1][1]);
      A2[2*j][0]   = pk_fma_blo(eb[j], x1lo, A2[2*j][0]);
      A2[2*j][1]   = pk_fma_blo(eb[j], x1hi, A2[2*j][1]);
      A2[2*j+1][0] = pk_fma_bhi(eb[j], x1lo, A2[2*j+1][0]);
      A2[2*j+1][1] = pk_fma_bhi(eb[j], x1hi, A2[2*j+1][1]);
    }
  }

  // epilogue: cross-wave reduce + normalize (R2-verified layout).
  __shared__ float As[4][8][256];  // 32 KB
  __shared__ float dws[4][8];
  __shared__ float dinvs[8];
  #pragma unroll
  for (int k = 0; k < 8; ++k) {
    float4 av;
    av.x = A2[k][0][0]; av.y = A2[k][0][1];
    av.z = A2[k][1][0]; av.w = A2[k][1][1];
    *reinterpret_cast<float4*>(&As[wv][k][4 * lane]) = av;
  }
  if ((lane & 7) == 0) dws[wv][h] = dacc;
  __syncthreads();
  if (t < 8) {
    float ds = dws[0][t] + dws[1][t] + dws[2][t] + dws[3][t];
    dinvs[t] = ds > 0.f ? 1.0f / ds : 0.f;
  }
  __syncthreads();
  #pragma unroll
  for (int r2 = 0; r2 < 8; ++r2) {
    float v = As[0][r2][t] + As[1][r2][t] + As[2][r2][t] + As[3][r2][t];
    Ag[(size_t)b * 2048 + r2 * 256 + t] = v * dinvs[r2];
  }
}

// ---------------- K5: att = A . Wv + bv (nonempty), out = att . Wo + bo
__global__ __launch_bounds__(256) void k_out(const float* __restrict__ Ag,
                                             const int* __restrict__ bounds,
                                             const float* __restrict__ Wv,
                                             const float* __restrict__ bv,
                                             const float* __restrict__ Wo,
                                             const float* __restrict__ bo,
                                             float* __restrict__ out) {
  __shared__ float Alds[4 * 2048];   // 32 KB
  __shared__ float attlds[4 * 256];  // 4 KB
  __shared__ float eflag[4];
  int b0 = blockIdx.x * 4;
  int t = threadIdx.x;
  #pragma unroll
  for (int r = 0; r < 32; ++r) {
    int idx = r * 256 + t;
    Alds[idx] = Ag[(size_t)b0 * 2048 + idx];
  }
  if (t < 4) {
    int s = bounds[2 * (b0 + t)], e = bounds[2 * (b0 + t) + 1];
    eflag[t] = (e > s) ? 1.0f : 0.0f;
  }
  __syncthreads();
  int h = t >> 5;
  float bvk = bv[t];
  float acc[4];
  #pragma unroll
  for (int g = 0; g < 4; ++g) acc[g] = 0.f;
  for (int i4 = 0; i4 < 64; ++i4) {
    float aa[4][4];
    #pragma unroll
    for (int g = 0; g < 4; ++g) {
      float4 v = *reinterpret_cast<const float4*>(&Alds[g * 2048 + h * 256 + i4 * 4]);
      aa[g][0] = v.x; aa[g][1] = v.y; aa[g][2] = v.z; aa[g][3] = v.w;
    }
    #pragma unroll
    for (int j = 0; j < 4; ++j) {
      float wvv = Wv[(size_t)(i4 * 4 + j) * 256 + t];
      #pragma unroll
      for (int g = 0; g < 4; ++g) acc[g] = fmaf(aa[g][j], wvv, acc[g]);
    }
  }
  #pragma unroll
  for (int g = 0; g < 4; ++g) attlds[g * 256 + t] = acc[g] + bvk * eflag[g];
  __syncthreads();
  float boj = bo[t];
  float o[4];
  #pragma unroll
  for (int g = 0; g < 4; ++g) o[g] = boj;
  for (int k4 = 0; k4 < 64; ++k4) {
    float aa[4][4];
    #pragma unroll
    for (int g = 0; g < 4; ++g) {
      float4 v = *reinterpret_cast<const float4*>(&attlds[g * 256 + k4 * 4]);
      aa[g][0] = v.x; aa[g][1] = v.y; aa[g][2] = v.z; aa[g][3] = v.w;
    }
    #pragma unroll
    for (int j = 0; j < 4; ++j) {
      float wo = Wo[(size_t)(k4 * 4 + j) * 256 + t];
      #pragma unroll
      for (int g = 0; g < 4; ++g) o[g] = fmaf(aa[g][j], wo, o[g]);
    }
  }
  #pragma unroll
  for (int g = 0; g < 4; ++g) out[(size_t)(b0 + g) * 256 + t] = o[g];
}

extern "C" void kernel_launch(void* const* d_in, const int* in_sizes, int n_in,
                              void* d_out, int out_size, void* d_ws, size_t ws_size,
                              hipStream_t stream) {
  const float* x   = (const float*)d_in[0];
  const int*   bat = (const int*)d_in[1];
  const float* q   = (const float*)d_in[2];
  const float* Wk  = (const float*)d_in[3];
  const float* bk  = (const float*)d_in[4];
  const float* Wv  = (const float*)d_in[5];
  const float* bv  = (const float*)d_in[6];
  const float* Wo  = (const float*)d_in[7];
  const float* bo  = (const float*)d_in[8];
  float* out = (float*)d_out;

  float* ws = (float*)d_ws;
  float* P      = ws;                 // 2048 floats
  float* c      = ws + 2048;          // 8 floats
  int*   bounds = (int*)(ws + 4096);  // 4096 ints
  float* Ag     = ws + 8192;          // 2048*2048 floats

  k_prep<<<8, 256, 0, stream>>>(Wk, bk, q, P, c);
  k_bounds<<<8, 256, 0, stream>>>(bat, bounds);
  k_fused<<<NGRAPH, 256, 0, stream>>>(x, P, c, bounds, Ag);
  k_out<<<NGRAPH / 4, 256, 0, stream>>>(Ag, bounds, Wv, bv, Wo, bo, out);
}